// Round 10
// baseline (195.638 us; speedup 1.0000x reference)
//
#include <hip/hip_runtime.h>
#include <hip/hip_bf16.h>

#define NEG_INF (-9999999.0f)

typedef __attribute__((ext_vector_type(8))) short bf16x8;
typedef __attribute__((ext_vector_type(4))) float f32x4;
typedef unsigned short us;

__device__ __forceinline__ float b2f(us u) {
  union { unsigned int i; float f; } x; x.i = ((unsigned int)u) << 16; return x.f;
}
__device__ __forceinline__ us f2b(float f) {
  union { float f; unsigned int i; } x; x.f = f;
  unsigned int r = x.i + 0x7fffu + ((x.i >> 16) & 1u);
  return (us)(r >> 16);
}
__device__ __forceinline__ float lrelu(float v) { return v > 0.f ? v : 0.01f * v; }
__device__ __forceinline__ bf16x8 ld8(const us* p) { return *reinterpret_cast<const bf16x8*>(p); }

// ---------------- prep ----------------
// tasks: 0-2 Ws/Wp/Wc -> padded bf16; 3: W_r -> W1b|W2b|W3b (contiguous, each [304][320]);
// 4: xg gather; 5: zero pads of encb/Pb/Cb; 6: zero encTb & Y2Tb rows 300-303; 7: r2 = W2 . root
__global__ __launch_bounds__(256) void k_prep(const int* __restrict__ wi, const float* __restrict__ E,
    const float* __restrict__ Ws, const float* __restrict__ Wp, const float* __restrict__ Wc,
    const float* __restrict__ Wr, const float* __restrict__ root,
    us* __restrict__ Wsb, us* __restrict__ Wpb, us* __restrict__ Wcb, us* __restrict__ Wspl,
    us* __restrict__ xg, us* __restrict__ encb, us* __restrict__ Pb, us* __restrict__ Cb,
    us* __restrict__ encTb, us* __restrict__ Y2Tb, float* __restrict__ r2) {
  int task = blockIdx.y;
  int gid = blockIdx.x * 256 + threadIdx.x;
  const int stride = 640 * 256;
  if (task < 3) {
    const float* src = (task == 0) ? Ws : (task == 1) ? Wp : Wc;
    us* dst = (task == 0) ? Wsb : (task == 1) ? Wpb : Wcb;
    for (int i = gid; i < 304 * 320; i += stride) {
      int r = i / 320, c = i - r * 320;
      dst[i] = (r < 300 && c < 300) ? f2b(src[r * 300 + c]) : 0;
    }
  } else if (task == 3) {
    for (int i = gid; i < 3 * 97280; i += stride) {
      int sub = i / 97280, rem = i - sub * 97280;
      int r = rem / 320, c = rem - r * 320;
      Wspl[i] = (r < 300 && c < 300) ? f2b(Wr[r * 900 + sub * 300 + c]) : 0;
    }
  } else if (task == 4) {
    for (int i = gid; i < 4096 * 320; i += stride) {
      int r = i / 320, c = i - r * 320;
      xg[i] = (c < 300) ? f2b(E[(long)wi[r * 64 + 63] * 300 + c]) : 0;
    }
  } else if (task == 5) {
    for (int i = gid; i < 3 * 4096 * 20; i += stride) {
      int b = i / 81920, rem = i - b * 81920;
      int r = rem / 20, c = 300 + (rem - r * 20);
      us* dst = (b == 0) ? encb : (b == 1) ? Pb : Cb;
      dst[r * 320 + c] = 0;
    }
  } else if (task == 6) {
    for (int i = gid; i < 2 * 4 * 4096; i += stride) {
      if (i < 16384) encTb[300 * 4096 + i] = 0;
      else           Y2Tb[300 * 4096 + (i - 16384)] = 0;
    }
  } else {
    if (gid < 300) {
      float s = 0.f;
      for (int w = 0; w < 300; ++w) s = fmaf(Wr[gid * 900 + 300 + w], root[w], s);
      r2[gid] = s;
    }
  }
}

// ---------------- stage a contiguous panel (units x 16B) into LDS ----------------
__device__ __forceinline__ void stage16(const us* __restrict__ g, us* lds, int units, int t) {
  const float4* s = reinterpret_cast<const float4*>(g);
  float4* d = reinterpret_cast<float4*>(lds);
  for (int i = t; i < units; i += 256) d[i] = s[i];
}

// ---------------- sweep with A from LDS (1-ahead), B from global (depth-3) ----------------
template<int NT, int KP>
__device__ __forceinline__ void sweep_lds(const us* As, const us* __restrict__ Bb,
    int bpitch, int nt0, int lo, int q, int ksn, f32x4* acc) {
  const us* ar = As + lo * KP + 8 * q;
  const us* br[NT];
#pragma unroll
  for (int t = 0; t < NT; ++t)
    br[t] = Bb + (long)((nt0 + t) * 16 + lo) * bpitch + 8 * q;
  bf16x8 b0[NT], b1[NT], b2[NT];
#pragma unroll
  for (int t = 0; t < NT; ++t) b0[t] = ld8(br[t]);
#pragma unroll
  for (int t = 0; t < NT; ++t) b1[t] = ld8(br[t] + 32);
#pragma unroll
  for (int t = 0; t < NT; ++t) b2[t] = ld8(br[t] + 64);
  bf16x8 a0 = *reinterpret_cast<const bf16x8*>(ar);
  for (int ks = 0; ks < ksn - 3; ++ks) {
    bf16x8 a1 = *reinterpret_cast<const bf16x8*>(ar + (ks + 1) * 32);
    bf16x8 bn[NT];
#pragma unroll
    for (int t = 0; t < NT; ++t) bn[t] = ld8(br[t] + (ks + 3) * 32);
#pragma unroll
    for (int t = 0; t < NT; ++t)
      acc[t] = __builtin_amdgcn_mfma_f32_16x16x32_bf16(a0, b0[t], acc[t], 0, 0, 0);
    a0 = a1;
#pragma unroll
    for (int t = 0; t < NT; ++t) { b0[t] = b1[t]; b1[t] = b2[t]; b2[t] = bn[t]; }
  }
  {
    bf16x8 a1 = *reinterpret_cast<const bf16x8*>(ar + (ksn - 2) * 32);
#pragma unroll
    for (int t = 0; t < NT; ++t)
      acc[t] = __builtin_amdgcn_mfma_f32_16x16x32_bf16(a0, b0[t], acc[t], 0, 0, 0);
    a0 = a1;
#pragma unroll
    for (int t = 0; t < NT; ++t) b0[t] = b1[t];
  }
  {
    bf16x8 a1 = *reinterpret_cast<const bf16x8*>(ar + (ksn - 1) * 32);
#pragma unroll
    for (int t = 0; t < NT; ++t)
      acc[t] = __builtin_amdgcn_mfma_f32_16x16x32_bf16(a0, b0[t], acc[t], 0, 0, 0);
    a0 = a1;
#pragma unroll
    for (int t = 0; t < NT; ++t) b0[t] = b2[t];
  }
#pragma unroll
  for (int t = 0; t < NT; ++t)
    acc[t] = __builtin_amdgcn_mfma_f32_16x16x32_bf16(a0, b0[t], acc[t], 0, 0, 0);
}

// ---------------- global-load sweep (depth-2) — used by k_attn ----------------
template<int NT>
__device__ __forceinline__ void sweep(const us* __restrict__ Ab, int apitch,
    const us* __restrict__ Bb, int bpitch, int m0, int nt0, int lo, int q,
    int ks0, int ksn, f32x4* acc) {
  const us* ar = Ab + (long)(m0 + lo) * apitch + 8 * q + (long)ks0 * 32;
  const us* br[NT];
#pragma unroll
  for (int t = 0; t < NT; ++t)
    br[t] = Bb + (long)((nt0 + t) * 16 + lo) * bpitch + 8 * q + (long)ks0 * 32;
  bf16x8 a0 = ld8(ar), a1 = ld8(ar + 32);
  bf16x8 b0[NT], b1[NT];
#pragma unroll
  for (int t = 0; t < NT; ++t) b0[t] = ld8(br[t]);
#pragma unroll
  for (int t = 0; t < NT; ++t) b1[t] = ld8(br[t] + 32);
  for (int ks = 0; ks < ksn - 2; ++ks) {
    bf16x8 a2 = ld8(ar + (ks + 2) * 32);
    bf16x8 b2[NT];
#pragma unroll
    for (int t = 0; t < NT; ++t) b2[t] = ld8(br[t] + (ks + 2) * 32);
#pragma unroll
    for (int t = 0; t < NT; ++t)
      acc[t] = __builtin_amdgcn_mfma_f32_16x16x32_bf16(a0, b0[t], acc[t], 0, 0, 0);
    a0 = a1; a1 = a2;
#pragma unroll
    for (int t = 0; t < NT; ++t) { b0[t] = b1[t]; b1[t] = b2[t]; }
  }
#pragma unroll
  for (int t = 0; t < NT; ++t)
    acc[t] = __builtin_amdgcn_mfma_f32_16x16x32_bf16(a0, b0[t], acc[t], 0, 0, 0);
#pragma unroll
  for (int t = 0; t < NT; ++t)
    acc[t] = __builtin_amdgcn_mfma_f32_16x16x32_bf16(a1, b1[t], acc[t], 0, 0, 0);
}

// ---------------- epilogues ----------------
template<int NT>
__device__ __forceinline__ void epi_bf16(const f32x4* acc, const float* __restrict__ bias,
    us* __restrict__ outb, us* __restrict__ outT,
    int m0, int nt0, int lo, int q) {
#pragma unroll
  for (int t = 0; t < NT; ++t) {
    int col = (nt0 + t) * 16 + lo;
    if (col >= 300) continue;
    float bb = bias[col];
#pragma unroll
    for (int r = 0; r < 4; ++r) {
      int row = m0 + q * 4 + r;
      us h = f2b(lrelu(acc[t][r] + bb));
      outb[(long)row * 320 + col] = h;
      if (outT) outT[(long)col * 4096 + row] = h;
    }
  }
}

template<int NT>
__device__ __forceinline__ void epi_f32lin(const f32x4* acc, float* __restrict__ out,
    int m0, int nt0, int lo, int q) {
#pragma unroll
  for (int t = 0; t < NT; ++t) {
    int col = (nt0 + t) * 16 + lo;
    if (col >= 300) continue;
#pragma unroll
    for (int r = 0; r < 4; ++r)
      out[(long)(m0 + q * 4 + r) * 300 + col] = acc[t][r];
  }
}

template<int NT>
__device__ __forceinline__ void epi_b16T(const f32x4* acc, us* __restrict__ outT,
    int m0, int nt0, int lo, int q) {
#pragma unroll
  for (int t = 0; t < NT; ++t) {
    int col = (nt0 + t) * 16 + lo;
    if (col >= 300) continue;
#pragma unroll
    for (int r = 0; r < 4; ++r)
      outT[(long)col * 4096 + m0 + q * 4 + r] = f2b(acc[t][r]);
  }
}

// ---------------- enc GEMM: LDS A panel ----------------
__global__ __launch_bounds__(256) void k_gemm_enc(const us* __restrict__ Ab,
    const us* __restrict__ Bb, const float* __restrict__ bias,
    us* __restrict__ encb, us* __restrict__ encTb) {
  __shared__ __align__(16) us As[16 * 320];
  int t = threadIdx.x;
  int m0 = blockIdx.x * 16;
  stage16(Ab + (long)m0 * 320, As, 640, t);
  __syncthreads();
  int w = t >> 6, lane = t & 63, lo = lane & 15, q = lane >> 4;
  f32x4 z = {0.f, 0.f, 0.f, 0.f};
  if (w < 3) {
    f32x4 acc[5] = {z, z, z, z, z};
    sweep_lds<5, 320>(As, Bb, 320, w * 5, lo, q, 10, acc);
    epi_bf16<5>(acc, bias, encb, encTb, m0, w * 5, lo, q);
  } else {
    f32x4 acc[4] = {z, z, z, z};
    sweep_lds<4, 320>(As, Bb, 320, 15, lo, q, 10, acc);
    epi_bf16<4>(acc, bias, encb, encTb, m0, 15, lo, q);
  }
}

// ---------------- big GEMM: grid (256, 5) over {P, C, Y2, Y1, Y3}; A = encb (LDS-staged) ----------------
__global__ __launch_bounds__(256) void k_big(const us* __restrict__ encb,
    const us* __restrict__ Wpb, const us* __restrict__ Wcb,
    const us* __restrict__ W1b, const us* __restrict__ W2b, const us* __restrict__ W3b,
    const float* __restrict__ bp, const float* __restrict__ bc,
    us* __restrict__ Pb, us* __restrict__ Cb,
    float* __restrict__ Y1, us* __restrict__ Y2Tb, float* __restrict__ Y3) {
  __shared__ __align__(16) us As[16 * 320];
  int t = threadIdx.x;
  int m0 = blockIdx.x * 16;
  int which = blockIdx.y;
  stage16(encb + (long)m0 * 320, As, 640, t);
  __syncthreads();
  int w = t >> 6, lane = t & 63, lo = lane & 15, q = lane >> 4;
  const us* Bb = (which == 0) ? Wpb : (which == 1) ? Wcb
               : (which == 2) ? W2b : (which == 3) ? W1b : W3b;
  f32x4 z = {0.f, 0.f, 0.f, 0.f};
  if (w < 3) {
    f32x4 acc[5] = {z, z, z, z, z};
    sweep_lds<5, 320>(As, Bb, 320, w * 5, lo, q, 10, acc);
    if (which == 0)      epi_bf16<5>(acc, bp, Pb, (us*)nullptr, m0, w * 5, lo, q);
    else if (which == 1) epi_bf16<5>(acc, bc, Cb, (us*)nullptr, m0, w * 5, lo, q);
    else if (which == 2) epi_b16T<5>(acc, Y2Tb, m0, w * 5, lo, q);
    else if (which == 3) epi_f32lin<5>(acc, Y1, m0, w * 5, lo, q);
    else                 epi_f32lin<5>(acc, Y3, m0, w * 5, lo, q);
  } else {
    f32x4 acc[4] = {z, z, z, z};
    sweep_lds<4, 320>(As, Bb, 320, 15, lo, q, 10, acc);
    if (which == 0)      epi_bf16<4>(acc, bp, Pb, (us*)nullptr, m0, 15, lo, q);
    else if (which == 1) epi_bf16<4>(acc, bc, Cb, (us*)nullptr, m0, 15, lo, q);
    else if (which == 2) epi_b16T<4>(acc, Y2Tb, m0, 15, lo, q);
    else if (which == 3) epi_f32lin<4>(acc, Y1, m0, 15, lo, q);
    else                 epi_f32lin<4>(acc, Y3, m0, 15, lo, q);
  }
}

// ---------------- attn: block (d, jg) owns a 64x16 logit slab; local column softmax ----------------
__global__ __launch_bounds__(256) void k_attn(
    const us* __restrict__ Pb, const us* __restrict__ Cb, const us* __restrict__ encb,
    const float* __restrict__ w_root, const float* __restrict__ b_root,
    float* __restrict__ Aout, float* __restrict__ outF,
    us* __restrict__ Atb, float* __restrict__ rsp) {
  __shared__ float Ls[64][17];
  __shared__ float pm[4][16], psum[4][16];
  __shared__ float scores[64];
  int d = blockIdx.x, jg = blockIdx.y, t = threadIdx.x;
  int w = t >> 6, lane = t & 63, lo = lane & 15, q = lane >> 4;

  if (jg == 0) {
    int rr = t >> 2, quad = t & 3;
    const us* er = encb + (long)(d * 64 + rr) * 320;
    float s = 0.f;
    for (int h = quad * 4; h + 4 <= 300; h += 16) {
      ushort4 e4 = *reinterpret_cast<const ushort4*>(er + h);
      s = fmaf(b2f(e4.x), w_root[h], s);
      s = fmaf(b2f(e4.y), w_root[h + 1], s);
      s = fmaf(b2f(e4.z), w_root[h + 2], s);
      s = fmaf(b2f(e4.w), w_root[h + 3], s);
    }
    s += __shfl_xor(s, 1);
    s += __shfl_xor(s, 2);
    if (quad == 0) scores[rr] = s + b_root[0];
    __syncthreads();
    if (t < 64) {
      float sc = scores[t];
      float m = sc;
#pragma unroll
      for (int o = 32; o > 0; o >>= 1) m = fmaxf(m, __shfl_xor(m, o, 64));
      float e = expf(sc - m);
      float sum = e;
#pragma unroll
      for (int o = 32; o > 0; o >>= 1) sum += __shfl_xor(sum, o, 64);
      outF[d * 64 + t] = e / sum;
    }
  }

  {
    const us* Pd = Pb + (long)d * 64 * 320;
    const us* Cd = Cb + (long)d * 64 * 320;
    f32x4 acc = {0.f, 0.f, 0.f, 0.f};
    sweep<1>(Pd, 320, Cd, 320, w * 16, jg, lo, q, 0, 10, &acc);
#pragma unroll
    for (int r = 0; r < 4; ++r) {
      int i = w * 16 + q * 4 + r, j = jg * 16 + lo;
      Ls[i][lo] = (i == j) ? NEG_INF : acc[r];
    }
  }
  __syncthreads();

  {
    int col = t & 15, p = t >> 4;
    if (t < 64) {
      float mx = -3.0e38f;
      for (int i = p * 16; i < p * 16 + 16; ++i) mx = fmaxf(mx, Ls[i][col]);
      pm[p][col] = mx;
    }
    __syncthreads();
    if (t < 64) {
      float gmx = fmaxf(fmaxf(pm[0][col], pm[1][col]), fmaxf(pm[2][col], pm[3][col]));
      float s = 0.f;
      for (int i = p * 16; i < p * 16 + 16; ++i) s += expf(Ls[i][col] - gmx);
      psum[p][col] = s;
    }
    __syncthreads();
    if (t < 64) {
      float gmx = fmaxf(fmaxf(pm[0][col], pm[1][col]), fmaxf(pm[2][col], pm[3][col]));
      float inv = 1.f / (psum[0][col] + psum[1][col] + psum[2][col] + psum[3][col]);
      int j = jg * 16 + col;
      float* Ad = Aout + (long)d * 4096;
      us* Atd = Atb + (long)d * 4096;
      for (int i = p * 16; i < p * 16 + 16; ++i) {
        float a = expf(Ls[i][col] - gmx) * inv;
        Ad[i * 64 + j] = a;
        Atd[j * 64 + i] = f2b(a);   // At[x][y] = A[y][x]
        Ls[i][col] = a;
      }
    }
  }
  __syncthreads();
  if (t < 64) {
    float s = 0.f;
#pragma unroll
    for (int c = 0; c < 16; ++c) s += Ls[t][c];
    rsp[(d * 4 + jg) * 64 + t] = s;
  }
}

// ---------------- comb: block (d, g); wave w -> h-tile g*4+w; ri = lrelu(Y1 + rs*Y3 + A^T.Y2 + fri*r2 + b_r) ----------------
__global__ __launch_bounds__(256) void k_comb(
    const us* __restrict__ Atb, const us* __restrict__ Y2Tb,
    const float* __restrict__ Y1, const float* __restrict__ Y3,
    const float* __restrict__ outF, const float* __restrict__ rsp,
    const float* __restrict__ r2, const float* __restrict__ b_r,
    float* __restrict__ ri) {
  __shared__ float frs[64], rs[64];
  int d = blockIdx.x, g = blockIdx.y, t = threadIdx.x;
  if (t < 64) {
    frs[t] = outF[d * 64 + t];
    rs[t] = rsp[(d * 4 + 0) * 64 + t] + rsp[(d * 4 + 1) * 64 + t]
          + rsp[(d * 4 + 2) * 64 + t] + rsp[(d * 4 + 3) * 64 + t];
  }
  __syncthreads();
  int w = t >> 6, lane = t & 63, lo = lane & 15, q = lane >> 4;
  int ht = g * 4 + w;
  if (ht >= 19) return;
  const us* Atd = Atb + (long)d * 4096;
  bf16x8 av0[4], av1[4];
#pragma unroll
  for (int mt = 0; mt < 4; ++mt) {
    av0[mt] = ld8(Atd + (mt * 16 + lo) * 64 + 8 * q);
    av1[mt] = ld8(Atd + (mt * 16 + lo) * 64 + 32 + 8 * q);
  }
  const us* brow = Y2Tb + (long)(ht * 16 + lo) * 4096 + d * 64 + 8 * q;
  bf16x8 bv0 = ld8(brow), bv1 = ld8(brow + 32);
  int h = ht * 16 + lo;
  float bb = (h < 300) ? b_r[h] : 0.f;
  float rr2 = (h < 300) ? r2[h] : 0.f;
#pragma unroll
  for (int mt = 0; mt < 4; ++mt) {
    f32x4 acc = {0.f, 0.f, 0.f, 0.f};
    acc = __builtin_amdgcn_mfma_f32_16x16x32_bf16(av0[mt], bv0, acc, 0, 0, 0);
    acc = __builtin_amdgcn_mfma_f32_16x16x32_bf16(av1[mt], bv1, acc, 0, 0, 0);
    if (h < 300) {
#pragma unroll
      for (int r = 0; r < 4; ++r) {
        int i = mt * 16 + q * 4 + r;
        long idx = (long)(d * 64 + i) * 300 + h;
        float v = Y1[idx] + rs[i] * Y3[idx] + acc[r] + frs[i] * rr2 + bb;
        ri[idx] = lrelu(v);
      }
    }
  }
}

// ---------------- final ----------------
__global__ __launch_bounds__(256) void k_final(const float* __restrict__ ri,
    const float* __restrict__ W_cls, const float* __restrict__ b_cls,
    float* __restrict__ outp) {
  __shared__ float fin[300];
  __shared__ float red[256];
  int d = blockIdx.x, t = threadIdx.x;
  for (int h = t; h < 300; h += 256) {
    float s = 0.f;
    for (int i = 0; i < 64; ++i) s += ri[((d * 64) + i) * 300 + h];
    fin[h] = s * (1.0f / 64.0f);
  }
  __syncthreads();
  for (int c2 = 0; c2 < 2; ++c2) {
    float pth = 0.f;
    for (int h = t; h < 300; h += 256) pth = fmaf(fin[h], W_cls[c2 * 300 + h], pth);
    red[t] = pth;
    __syncthreads();
    for (int o = 128; o > 0; o >>= 1) {
      if (t < o) red[t] += red[t + o];
      __syncthreads();
    }
    if (t == 0) outp[d * 2 + c2] = red[0] + b_cls[c2];
    __syncthreads();
  }
}

extern "C" void kernel_launch(void* const* d_in, const int* in_sizes, int n_in,
                              void* d_out, int out_size, void* d_ws, size_t ws_size,
                              hipStream_t stream) {
  const int*   wi     = (const int*)d_in[0];
  const float* E      = (const float*)d_in[1];
  const float* W_sent = (const float*)d_in[2];
  const float* b_sent = (const float*)d_in[3];
  const float* W_par  = (const float*)d_in[4];
  const float* b_par  = (const float*)d_in[5];
  const float* W_ch   = (const float*)d_in[6];
  const float* b_ch   = (const float*)d_in[7];
  const float* w_root = (const float*)d_in[8];
  const float* b_root = (const float*)d_in[9];
  const float* root_e = (const float*)d_in[10];
  const float* W_r    = (const float*)d_in[11];
  const float* b_r    = (const float*)d_in[12];
  const float* W_cls  = (const float*)d_in[13];
  const float* b_cls  = (const float*)d_in[14];

  us* B = (us*)d_ws;
  us* Wsb   = B;                 //  97280  [304][320]
  us* Wpb   = B + 97280;
  us* Wcb   = B + 194560;
  us* Wspl  = B + 291840;        // W1b|W2b|W3b, 3 x 97280
  us* W1b   = Wspl;
  us* W2b   = Wspl + 97280;
  us* W3b   = Wspl + 194560;
  us* xg    = B + 583680;        // 1310720 [4096][320]
  us* encb  = B + 1894400;       // 1310720
  us* encTb = B + 3205120;       // 1245184 [304][4096]
  us* Pb    = B + 4450304;       // 1310720
  us* Cb    = B + 5761024;       // 1310720
  us* Y2Tb  = B + 7071744;       // 1245184 [304][4096]
  us* Atb   = B + 8316928;       // 262144  [64][64][64] bf16 A^T
  float* rsp = (float*)(B + 8579072);   // [64][4][64]
  float* r2  = (float*)(B + 8611840);   // [300]
  float* Y1  = (float*)(B + 8612440);   // [4096][300]
  float* Y3  = (float*)(B + 11070040);  // [4096][300]
  float* ri  = (float*)(B + 13527640);  // [4096][300]

  float* outp = (float*)d_out;   // [out(128) | A(262144) | fri(4096)]
  float* outA = outp + 128;
  float* outF = outp + 128 + 262144;

  k_prep<<<dim3(640, 8), 256, 0, stream>>>(wi, E, W_sent, W_par, W_ch, W_r, root_e,
                                           Wsb, Wpb, Wcb, Wspl, xg, encb, Pb, Cb,
                                           encTb, Y2Tb, r2);
  k_gemm_enc<<<256, 256, 0, stream>>>(xg, Wsb, b_sent, encb, encTb);
  k_big<<<dim3(256, 5), 256, 0, stream>>>(encb, Wpb, Wcb, W1b, W2b, W3b,
                                          b_par, b_ch, Pb, Cb, Y1, Y2Tb, Y3);
  k_attn<<<dim3(64, 4), 256, 0, stream>>>(Pb, Cb, encb, w_root, b_root,
                                          outA, outF, Atb, rsp);
  k_comb<<<dim3(64, 5), 256, 0, stream>>>(Atb, Y2Tb, Y1, Y3, outF, rsp, r2, b_r, ri);
  k_final<<<64, 256, 0, stream>>>(ri, W_cls, b_cls, outp);
}

// Round 11
// 190.376 us; speedup vs baseline: 1.0276x; 1.0276x over previous
//
#include <hip/hip_runtime.h>
#include <hip/hip_bf16.h>

#define NEG_INF (-9999999.0f)

typedef __attribute__((ext_vector_type(8))) short bf16x8;
typedef __attribute__((ext_vector_type(4))) float f32x4;
typedef unsigned short us;

__device__ __forceinline__ float b2f(us u) {
  union { unsigned int i; float f; } x; x.i = ((unsigned int)u) << 16; return x.f;
}
__device__ __forceinline__ us f2b(float f) {
  union { float f; unsigned int i; } x; x.f = f;
  unsigned int r = x.i + 0x7fffu + ((x.i >> 16) & 1u);
  return (us)(r >> 16);
}
__device__ __forceinline__ float lrelu(float v) { return v > 0.f ? v : 0.01f * v; }
__device__ __forceinline__ bf16x8 ld8(const us* p) { return *reinterpret_cast<const bf16x8*>(p); }

// ---------------- prep ----------------
// tasks: 0-2 Ws/Wp/Wc -> padded bf16; 3: W_r -> W1b|W2b|W3b; 4: xg gather;
// 5: zero pads of encb/Pb/Cb; 6: zero encTb & Y2Tb rows 300-303; 7: r2 = W2 . root
__global__ __launch_bounds__(256) void k_prep(const int* __restrict__ wi, const float* __restrict__ E,
    const float* __restrict__ Ws, const float* __restrict__ Wp, const float* __restrict__ Wc,
    const float* __restrict__ Wr, const float* __restrict__ root,
    us* __restrict__ Wsb, us* __restrict__ Wpb, us* __restrict__ Wcb, us* __restrict__ Wspl,
    us* __restrict__ xg, us* __restrict__ encb, us* __restrict__ Pb, us* __restrict__ Cb,
    us* __restrict__ encTb, us* __restrict__ Y2Tb, float* __restrict__ r2) {
  int task = blockIdx.y;
  int gid = blockIdx.x * 256 + threadIdx.x;
  const int stride = 640 * 256;
  if (task < 3) {
    const float* src = (task == 0) ? Ws : (task == 1) ? Wp : Wc;
    us* dst = (task == 0) ? Wsb : (task == 1) ? Wpb : Wcb;
    for (int i = gid; i < 304 * 320; i += stride) {
      int r = i / 320, c = i - r * 320;
      dst[i] = (r < 300 && c < 300) ? f2b(src[r * 300 + c]) : 0;
    }
  } else if (task == 3) {
    for (int i = gid; i < 3 * 97280; i += stride) {
      int sub = i / 97280, rem = i - sub * 97280;
      int r = rem / 320, c = rem - r * 320;
      Wspl[i] = (r < 300 && c < 300) ? f2b(Wr[r * 900 + sub * 300 + c]) : 0;
    }
  } else if (task == 4) {
    for (int i = gid; i < 4096 * 320; i += stride) {
      int r = i / 320, c = i - r * 320;
      xg[i] = (c < 300) ? f2b(E[(long)wi[r * 64 + 63] * 300 + c]) : 0;
    }
  } else if (task == 5) {
    for (int i = gid; i < 3 * 4096 * 20; i += stride) {
      int b = i / 81920, rem = i - b * 81920;
      int r = rem / 20, c = 300 + (rem - r * 20);
      us* dst = (b == 0) ? encb : (b == 1) ? Pb : Cb;
      dst[r * 320 + c] = 0;
    }
  } else if (task == 6) {
    for (int i = gid; i < 2 * 4 * 4096; i += stride) {
      if (i < 16384) encTb[300 * 4096 + i] = 0;
      else           Y2Tb[300 * 4096 + (i - 16384)] = 0;
    }
  } else {
    if (gid < 300) {
      float s = 0.f;
      for (int w = 0; w < 300; ++w) s = fmaf(Wr[gid * 900 + 300 + w], root[w], s);
      r2[gid] = s;
    }
  }
}

// ---------------- stage a contiguous panel (units x 16B) into LDS ----------------
__device__ __forceinline__ void stage16(const us* __restrict__ g, us* lds, int units, int t) {
  const float4* s = reinterpret_cast<const float4*>(g);
  float4* d = reinterpret_cast<float4*>(lds);
  for (int i = t; i < units; i += 256) d[i] = s[i];
}

// ---------------- sweep with A from LDS (1-ahead), B from global (depth-3) ----------------
template<int NT, int KP>
__device__ __forceinline__ void sweep_lds(const us* As, const us* __restrict__ Bb,
    int bpitch, int nt0, int lo, int q, int ksn, f32x4* acc) {
  const us* ar = As + lo * KP + 8 * q;
  const us* br[NT];
#pragma unroll
  for (int t = 0; t < NT; ++t)
    br[t] = Bb + (long)((nt0 + t) * 16 + lo) * bpitch + 8 * q;
  bf16x8 b0[NT], b1[NT], b2[NT];
#pragma unroll
  for (int t = 0; t < NT; ++t) b0[t] = ld8(br[t]);
#pragma unroll
  for (int t = 0; t < NT; ++t) b1[t] = ld8(br[t] + 32);
#pragma unroll
  for (int t = 0; t < NT; ++t) b2[t] = ld8(br[t] + 64);
  bf16x8 a0 = *reinterpret_cast<const bf16x8*>(ar);
  for (int ks = 0; ks < ksn - 3; ++ks) {
    bf16x8 a1 = *reinterpret_cast<const bf16x8*>(ar + (ks + 1) * 32);
    bf16x8 bn[NT];
#pragma unroll
    for (int t = 0; t < NT; ++t) bn[t] = ld8(br[t] + (ks + 3) * 32);
#pragma unroll
    for (int t = 0; t < NT; ++t)
      acc[t] = __builtin_amdgcn_mfma_f32_16x16x32_bf16(a0, b0[t], acc[t], 0, 0, 0);
    a0 = a1;
#pragma unroll
    for (int t = 0; t < NT; ++t) { b0[t] = b1[t]; b1[t] = b2[t]; b2[t] = bn[t]; }
  }
  {
    bf16x8 a1 = *reinterpret_cast<const bf16x8*>(ar + (ksn - 2) * 32);
#pragma unroll
    for (int t = 0; t < NT; ++t)
      acc[t] = __builtin_amdgcn_mfma_f32_16x16x32_bf16(a0, b0[t], acc[t], 0, 0, 0);
    a0 = a1;
#pragma unroll
    for (int t = 0; t < NT; ++t) b0[t] = b1[t];
  }
  {
    bf16x8 a1 = *reinterpret_cast<const bf16x8*>(ar + (ksn - 1) * 32);
#pragma unroll
    for (int t = 0; t < NT; ++t)
      acc[t] = __builtin_amdgcn_mfma_f32_16x16x32_bf16(a0, b0[t], acc[t], 0, 0, 0);
    a0 = a1;
#pragma unroll
    for (int t = 0; t < NT; ++t) b0[t] = b2[t];
  }
#pragma unroll
  for (int t = 0; t < NT; ++t)
    acc[t] = __builtin_amdgcn_mfma_f32_16x16x32_bf16(a0, b0[t], acc[t], 0, 0, 0);
}

// ---------------- global-load sweep (depth-2) — used by k_attn ----------------
template<int NT>
__device__ __forceinline__ void sweep(const us* __restrict__ Ab, int apitch,
    const us* __restrict__ Bb, int bpitch, int m0, int nt0, int lo, int q,
    int ks0, int ksn, f32x4* acc) {
  const us* ar = Ab + (long)(m0 + lo) * apitch + 8 * q + (long)ks0 * 32;
  const us* br[NT];
#pragma unroll
  for (int t = 0; t < NT; ++t)
    br[t] = Bb + (long)((nt0 + t) * 16 + lo) * bpitch + 8 * q + (long)ks0 * 32;
  bf16x8 a0 = ld8(ar), a1 = ld8(ar + 32);
  bf16x8 b0[NT], b1[NT];
#pragma unroll
  for (int t = 0; t < NT; ++t) b0[t] = ld8(br[t]);
#pragma unroll
  for (int t = 0; t < NT; ++t) b1[t] = ld8(br[t] + 32);
  for (int ks = 0; ks < ksn - 2; ++ks) {
    bf16x8 a2 = ld8(ar + (ks + 2) * 32);
    bf16x8 b2[NT];
#pragma unroll
    for (int t = 0; t < NT; ++t) b2[t] = ld8(br[t] + (ks + 2) * 32);
#pragma unroll
    for (int t = 0; t < NT; ++t)
      acc[t] = __builtin_amdgcn_mfma_f32_16x16x32_bf16(a0, b0[t], acc[t], 0, 0, 0);
    a0 = a1; a1 = a2;
#pragma unroll
    for (int t = 0; t < NT; ++t) { b0[t] = b1[t]; b1[t] = b2[t]; }
  }
#pragma unroll
  for (int t = 0; t < NT; ++t)
    acc[t] = __builtin_amdgcn_mfma_f32_16x16x32_bf16(a0, b0[t], acc[t], 0, 0, 0);
#pragma unroll
  for (int t = 0; t < NT; ++t)
    acc[t] = __builtin_amdgcn_mfma_f32_16x16x32_bf16(a1, b1[t], acc[t], 0, 0, 0);
}

// ---------------- epilogues ----------------
template<int NT>
__device__ __forceinline__ void epi_bf16(const f32x4* acc, const float* __restrict__ bias,
    us* __restrict__ outb, us* __restrict__ outT,
    int m0, int nt0, int lo, int q) {
#pragma unroll
  for (int t = 0; t < NT; ++t) {
    int col = (nt0 + t) * 16 + lo;
    if (col >= 300) continue;
    float bb = bias[col];
#pragma unroll
    for (int r = 0; r < 4; ++r) {
      int row = m0 + q * 4 + r;
      us h = f2b(lrelu(acc[t][r] + bb));
      outb[(long)row * 320 + col] = h;
      if (outT) outT[(long)col * 4096 + row] = h;
    }
  }
}

template<int NT>
__device__ __forceinline__ void epi_b16lin(const f32x4* acc, us* __restrict__ out,
    int m0, int nt0, int lo, int q) {
#pragma unroll
  for (int t = 0; t < NT; ++t) {
    int col = (nt0 + t) * 16 + lo;
    if (col >= 300) continue;
#pragma unroll
    for (int r = 0; r < 4; ++r)
      out[(long)(m0 + q * 4 + r) * 300 + col] = f2b(acc[t][r]);
  }
}

template<int NT>
__device__ __forceinline__ void epi_b16T(const f32x4* acc, us* __restrict__ outT,
    int m0, int nt0, int lo, int q) {
#pragma unroll
  for (int t = 0; t < NT; ++t) {
    int col = (nt0 + t) * 16 + lo;
    if (col >= 300) continue;
#pragma unroll
    for (int r = 0; r < 4; ++r)
      outT[(long)col * 4096 + m0 + q * 4 + r] = f2b(acc[t][r]);
  }
}

// ---------------- enc GEMM: LDS A panel ----------------
__global__ __launch_bounds__(256) void k_gemm_enc(const us* __restrict__ Ab,
    const us* __restrict__ Bb, const float* __restrict__ bias,
    us* __restrict__ encb, us* __restrict__ encTb) {
  __shared__ __align__(16) us As[16 * 320];
  int t = threadIdx.x;
  int m0 = blockIdx.x * 16;
  stage16(Ab + (long)m0 * 320, As, 640, t);
  __syncthreads();
  int w = t >> 6, lane = t & 63, lo = lane & 15, q = lane >> 4;
  f32x4 z = {0.f, 0.f, 0.f, 0.f};
  if (w < 3) {
    f32x4 acc[5] = {z, z, z, z, z};
    sweep_lds<5, 320>(As, Bb, 320, w * 5, lo, q, 10, acc);
    epi_bf16<5>(acc, bias, encb, encTb, m0, w * 5, lo, q);
  } else {
    f32x4 acc[4] = {z, z, z, z};
    sweep_lds<4, 320>(As, Bb, 320, 15, lo, q, 10, acc);
    epi_bf16<4>(acc, bias, encb, encTb, m0, 15, lo, q);
  }
}

// ---------------- big GEMM: grid (256, 5) over {P, C, Y2, Y1, Y3}; A = encb (LDS-staged) ----------------
__global__ __launch_bounds__(256) void k_big(const us* __restrict__ encb,
    const us* __restrict__ Wpb, const us* __restrict__ Wcb,
    const us* __restrict__ W1b, const us* __restrict__ W2b, const us* __restrict__ W3b,
    const float* __restrict__ bp, const float* __restrict__ bc,
    us* __restrict__ Pb, us* __restrict__ Cb,
    us* __restrict__ Y1b, us* __restrict__ Y2Tb, us* __restrict__ Y3b) {
  __shared__ __align__(16) us As[16 * 320];
  int t = threadIdx.x;
  int m0 = blockIdx.x * 16;
  int which = blockIdx.y;
  stage16(encb + (long)m0 * 320, As, 640, t);
  __syncthreads();
  int w = t >> 6, lane = t & 63, lo = lane & 15, q = lane >> 4;
  const us* Bb = (which == 0) ? Wpb : (which == 1) ? Wcb
               : (which == 2) ? W2b : (which == 3) ? W1b : W3b;
  f32x4 z = {0.f, 0.f, 0.f, 0.f};
  if (w < 3) {
    f32x4 acc[5] = {z, z, z, z, z};
    sweep_lds<5, 320>(As, Bb, 320, w * 5, lo, q, 10, acc);
    if (which == 0)      epi_bf16<5>(acc, bp, Pb, (us*)nullptr, m0, w * 5, lo, q);
    else if (which == 1) epi_bf16<5>(acc, bc, Cb, (us*)nullptr, m0, w * 5, lo, q);
    else if (which == 2) epi_b16T<5>(acc, Y2Tb, m0, w * 5, lo, q);
    else if (which == 3) epi_b16lin<5>(acc, Y1b, m0, w * 5, lo, q);
    else                 epi_b16lin<5>(acc, Y3b, m0, w * 5, lo, q);
  } else {
    f32x4 acc[4] = {z, z, z, z};
    sweep_lds<4, 320>(As, Bb, 320, 15, lo, q, 10, acc);
    if (which == 0)      epi_bf16<4>(acc, bp, Pb, (us*)nullptr, m0, 15, lo, q);
    else if (which == 1) epi_bf16<4>(acc, bc, Cb, (us*)nullptr, m0, 15, lo, q);
    else if (which == 2) epi_b16T<4>(acc, Y2Tb, m0, 15, lo, q);
    else if (which == 3) epi_b16lin<4>(acc, Y1b, m0, 15, lo, q);
    else                 epi_b16lin<4>(acc, Y3b, m0, 15, lo, q);
  }
}

// ---------------- attn: block (d, jg) owns a 64x16 logit slab; local column softmax ----------------
__global__ __launch_bounds__(256) void k_attn(
    const us* __restrict__ Pb, const us* __restrict__ Cb, const us* __restrict__ encb,
    const float* __restrict__ w_root, const float* __restrict__ b_root,
    float* __restrict__ Aout, float* __restrict__ outF,
    us* __restrict__ Atb, float* __restrict__ rsp) {
  __shared__ float Ls[64][17];
  __shared__ float pm[4][16], psum[4][16];
  __shared__ float scores[64];
  int d = blockIdx.x, jg = blockIdx.y, t = threadIdx.x;
  int w = t >> 6, lane = t & 63, lo = lane & 15, q = lane >> 4;

  if (jg == 0) {
    int rr = t >> 2, quad = t & 3;
    const us* er = encb + (long)(d * 64 + rr) * 320;
    float s = 0.f;
    for (int h = quad * 4; h + 4 <= 300; h += 16) {
      ushort4 e4 = *reinterpret_cast<const ushort4*>(er + h);
      s = fmaf(b2f(e4.x), w_root[h], s);
      s = fmaf(b2f(e4.y), w_root[h + 1], s);
      s = fmaf(b2f(e4.z), w_root[h + 2], s);
      s = fmaf(b2f(e4.w), w_root[h + 3], s);
    }
    s += __shfl_xor(s, 1);
    s += __shfl_xor(s, 2);
    if (quad == 0) scores[rr] = s + b_root[0];
    __syncthreads();
    if (t < 64) {
      float sc = scores[t];
      float m = sc;
#pragma unroll
      for (int o = 32; o > 0; o >>= 1) m = fmaxf(m, __shfl_xor(m, o, 64));
      float e = expf(sc - m);
      float sum = e;
#pragma unroll
      for (int o = 32; o > 0; o >>= 1) sum += __shfl_xor(sum, o, 64);
      outF[d * 64 + t] = e / sum;
    }
  }

  {
    const us* Pd = Pb + (long)d * 64 * 320;
    const us* Cd = Cb + (long)d * 64 * 320;
    f32x4 acc = {0.f, 0.f, 0.f, 0.f};
    sweep<1>(Pd, 320, Cd, 320, w * 16, jg, lo, q, 0, 10, &acc);
#pragma unroll
    for (int r = 0; r < 4; ++r) {
      int i = w * 16 + q * 4 + r, j = jg * 16 + lo;
      Ls[i][lo] = (i == j) ? NEG_INF : acc[r];
    }
  }
  __syncthreads();

  {
    int col = t & 15, p = t >> 4;
    if (t < 64) {
      float mx = -3.0e38f;
      for (int i = p * 16; i < p * 16 + 16; ++i) mx = fmaxf(mx, Ls[i][col]);
      pm[p][col] = mx;
    }
    __syncthreads();
    if (t < 64) {
      float gmx = fmaxf(fmaxf(pm[0][col], pm[1][col]), fmaxf(pm[2][col], pm[3][col]));
      float s = 0.f;
      for (int i = p * 16; i < p * 16 + 16; ++i) s += expf(Ls[i][col] - gmx);
      psum[p][col] = s;
    }
    __syncthreads();
    if (t < 64) {
      float gmx = fmaxf(fmaxf(pm[0][col], pm[1][col]), fmaxf(pm[2][col], pm[3][col]));
      float inv = 1.f / (psum[0][col] + psum[1][col] + psum[2][col] + psum[3][col]);
      int j = jg * 16 + col;
      float* Ad = Aout + (long)d * 4096;
      us* Atd = Atb + (long)d * 4096;
      for (int i = p * 16; i < p * 16 + 16; ++i) {
        float a = expf(Ls[i][col] - gmx) * inv;
        Ad[i * 64 + j] = a;
        Atd[j * 64 + i] = f2b(a);   // At[x][y] = A[y][x]
        Ls[i][col] = a;
      }
    }
  }
  __syncthreads();
  if (t < 64) {
    float s = 0.f;
#pragma unroll
    for (int c = 0; c < 16; ++c) s += Ls[t][c];
    rsp[(d * 4 + jg) * 64 + t] = s;
  }
}

// ---------------- comb: block (d, g); wave w -> h-tile g*4+w; ri = lrelu(Y1 + rs*Y3 + A^T.Y2 + fri*r2 + b_r) ----------------
__global__ __launch_bounds__(256) void k_comb(
    const us* __restrict__ Atb, const us* __restrict__ Y2Tb,
    const us* __restrict__ Y1b, const us* __restrict__ Y3b,
    const float* __restrict__ outF, const float* __restrict__ rsp,
    const float* __restrict__ r2, const float* __restrict__ b_r,
    float* __restrict__ ri) {
  __shared__ float frs[64], rs[64];
  int d = blockIdx.x, g = blockIdx.y, t = threadIdx.x;
  if (t < 64) {
    frs[t] = outF[d * 64 + t];
    rs[t] = rsp[(d * 4 + 0) * 64 + t] + rsp[(d * 4 + 1) * 64 + t]
          + rsp[(d * 4 + 2) * 64 + t] + rsp[(d * 4 + 3) * 64 + t];
  }
  __syncthreads();
  int w = t >> 6, lane = t & 63, lo = lane & 15, q = lane >> 4;
  int ht = g * 4 + w;
  if (ht >= 19) return;
  const us* Atd = Atb + (long)d * 4096;
  bf16x8 av0[4], av1[4];
#pragma unroll
  for (int mt = 0; mt < 4; ++mt) {
    av0[mt] = ld8(Atd + (mt * 16 + lo) * 64 + 8 * q);
    av1[mt] = ld8(Atd + (mt * 16 + lo) * 64 + 32 + 8 * q);
  }
  const us* brow = Y2Tb + (long)(ht * 16 + lo) * 4096 + d * 64 + 8 * q;
  bf16x8 bv0 = ld8(brow), bv1 = ld8(brow + 32);
  int h = ht * 16 + lo;
  float bb = (h < 300) ? b_r[h] : 0.f;
  float rr2 = (h < 300) ? r2[h] : 0.f;
#pragma unroll
  for (int mt = 0; mt < 4; ++mt) {
    f32x4 acc = {0.f, 0.f, 0.f, 0.f};
    acc = __builtin_amdgcn_mfma_f32_16x16x32_bf16(av0[mt], bv0, acc, 0, 0, 0);
    acc = __builtin_amdgcn_mfma_f32_16x16x32_bf16(av1[mt], bv1, acc, 0, 0, 0);
    if (h < 300) {
#pragma unroll
      for (int r = 0; r < 4; ++r) {
        int i = mt * 16 + q * 4 + r;
        long idx = (long)(d * 64 + i) * 300 + h;
        float v = b2f(Y1b[idx]) + rs[i] * b2f(Y3b[idx]) + acc[r] + frs[i] * rr2 + bb;
        ri[idx] = lrelu(v);
      }
    }
  }
}

// ---------------- final: 4-way ILP on the i-reduction ----------------
__global__ __launch_bounds__(256) void k_final(const float* __restrict__ ri,
    const float* __restrict__ W_cls, const float* __restrict__ b_cls,
    float* __restrict__ outp) {
  __shared__ float fin[300];
  __shared__ float red[256];
  int d = blockIdx.x, t = threadIdx.x;
  for (int h = t; h < 300; h += 256) {
    float s0 = 0.f, s1 = 0.f, s2 = 0.f, s3 = 0.f;
    const float* base = ri + (long)(d * 64) * 300 + h;
    for (int i = 0; i < 64; i += 4) {
      s0 += base[(i + 0) * 300];
      s1 += base[(i + 1) * 300];
      s2 += base[(i + 2) * 300];
      s3 += base[(i + 3) * 300];
    }
    fin[h] = (s0 + s1 + s2 + s3) * (1.0f / 64.0f);
  }
  __syncthreads();
  for (int c2 = 0; c2 < 2; ++c2) {
    float pth = 0.f;
    for (int h = t; h < 300; h += 256) pth = fmaf(fin[h], W_cls[c2 * 300 + h], pth);
    red[t] = pth;
    __syncthreads();
    for (int o = 128; o > 0; o >>= 1) {
      if (t < o) red[t] += red[t + o];
      __syncthreads();
    }
    if (t == 0) outp[d * 2 + c2] = red[0] + b_cls[c2];
    __syncthreads();
  }
}

extern "C" void kernel_launch(void* const* d_in, const int* in_sizes, int n_in,
                              void* d_out, int out_size, void* d_ws, size_t ws_size,
                              hipStream_t stream) {
  const int*   wi     = (const int*)d_in[0];
  const float* E      = (const float*)d_in[1];
  const float* W_sent = (const float*)d_in[2];
  const float* b_sent = (const float*)d_in[3];
  const float* W_par  = (const float*)d_in[4];
  const float* b_par  = (const float*)d_in[5];
  const float* W_ch   = (const float*)d_in[6];
  const float* b_ch   = (const float*)d_in[7];
  const float* w_root = (const float*)d_in[8];
  const float* b_root = (const float*)d_in[9];
  const float* root_e = (const float*)d_in[10];
  const float* W_r    = (const float*)d_in[11];
  const float* b_r    = (const float*)d_in[12];
  const float* W_cls  = (const float*)d_in[13];
  const float* b_cls  = (const float*)d_in[14];

  us* B = (us*)d_ws;
  us* Wsb   = B;                 //  97280  [304][320]
  us* Wpb   = B + 97280;
  us* Wcb   = B + 194560;
  us* Wspl  = B + 291840;        // W1b|W2b|W3b, 3 x 97280
  us* W1b   = Wspl;
  us* W2b   = Wspl + 97280;
  us* W3b   = Wspl + 194560;
  us* xg    = B + 583680;        // 1310720 [4096][320]
  us* encb  = B + 1894400;       // 1310720
  us* encTb = B + 3205120;       // 1245184 [304][4096]
  us* Pb    = B + 4450304;       // 1310720
  us* Cb    = B + 5761024;       // 1310720
  us* Y2Tb  = B + 7071744;       // 1245184 [304][4096]
  us* Atb   = B + 8316928;       // 262144  [64][64][64] bf16 A^T
  float* rsp = (float*)(B + 8579072);   // [64][4][64]
  float* r2  = (float*)(B + 8611840);   // [300]
  us* Y1b   = B + 8612440;       // 1228800 [4096][300] bf16
  us* Y3b   = B + 9841240;       // 1228800
  float* ri  = (float*)(B + 11070040);  // [4096][300] fp32

  float* outp = (float*)d_out;   // [out(128) | A(262144) | fri(4096)]
  float* outA = outp + 128;
  float* outF = outp + 128 + 262144;

  k_prep<<<dim3(640, 8), 256, 0, stream>>>(wi, E, W_sent, W_par, W_ch, W_r, root_e,
                                           Wsb, Wpb, Wcb, Wspl, xg, encb, Pb, Cb,
                                           encTb, Y2Tb, r2);
  k_gemm_enc<<<256, 256, 0, stream>>>(xg, Wsb, b_sent, encb, encTb);
  k_big<<<dim3(256, 5), 256, 0, stream>>>(encb, Wpb, Wcb, W1b, W2b, W3b,
                                          b_par, b_ch, Pb, Cb, Y1b, Y2Tb, Y3b);
  k_attn<<<dim3(64, 4), 256, 0, stream>>>(Pb, Cb, encb, w_root, b_root,
                                          outA, outF, Atb, rsp);
  k_comb<<<dim3(64, 5), 256, 0, stream>>>(Atb, Y2Tb, Y1b, Y3b, outF, rsp, r2, b_r, ri);
  k_final<<<64, 256, 0, stream>>>(ri, W_cls, b_cls, outp);
}